// Round 4
// baseline (130.878 us; speedup 1.0000x reference)
//
#include <hip/hip_runtime.h>
#include <hip/hip_bf16.h>

#define N 8192
#define D 128
#define WEIGHT 0.01f
#define NTILES 64            // N / 128
#define NBLK 2080            // NTILES*(NTILES+1)/2

typedef __bf16 bf16x8 __attribute__((ext_vector_type(8)));
typedef float floatx4 __attribute__((ext_vector_type(4)));

// ---- Kernel 1: L2-normalize rows (fp32), store bf16.
__global__ __launch_bounds__(256) void k_norm(const float* __restrict__ x,
                                              __hip_bfloat16* __restrict__ fb) {
    int gid = blockIdx.x * 256 + threadIdx.x;   // 2048 blocks -> 8192 waves
    int row = gid >> 6;
    int lane = gid & 63;
    const float* xr = x + row * D;
    float a0 = xr[lane];
    float a1 = xr[lane + 64];
    float s = a0 * a0 + a1 * a1;
    #pragma unroll
    for (int m = 1; m < 64; m <<= 1) s += __shfl_xor(s, m, 64);
    float inv = 1.0f / fmaxf(sqrtf(s), 1e-12f);
    fb[row * D + lane]      = __float2bfloat16(a0 * inv);
    fb[row * D + lane + 64] = __float2bfloat16(a1 * inv);
}

// ---- Kernel 2: upper-triangle 128x128 tiles of sim = F F^T.
//      No LDS tile staging: A/B fragments loaded b128 straight from L2
//      (fb is 2 MB, fully L2-resident; K=128 is too short to amortize LDS).
//      No K-loop barrier. 8 waves (2x4), wave tile 64x32.
//      launch_bounds(512,6): target ~85 VGPR -> 3 blocks/CU = 24 waves/CU.
__global__ __launch_bounds__(512, 6) void k_gram(const __hip_bfloat16* __restrict__ fb,
                                                 float* __restrict__ Prow,
                                                 float* __restrict__ Pcol,
                                                 float* __restrict__ p,
                                                 float* __restrict__ ep) {
    // Decode triangular linear index -> (bi, bj), bj >= bi.
    int b = blockIdx.x;                  // 0 .. 2079
    int bi = (int)((2.0 * NTILES + 1.0 - sqrt((2.0 * NTILES + 1.0) * (2.0 * NTILES + 1.0) - 8.0 * (double)b)) * 0.5);
    while (bi * NTILES - bi * (bi - 1) / 2 > b) --bi;
    while ((bi + 1) * NTILES - (bi + 1) * bi / 2 <= b) ++bi;
    int bj = bi + (b - (bi * NTILES - bi * (bi - 1) / 2));

    __shared__ float PR[4][128];         // per-wcol row partials
    __shared__ float PC[2][128];         // per-wrow col partials

    const int t = threadIdx.x;
    const int lane = t & 63;
    const int wid  = t >> 6;             // 8 waves: 2x4; wave tile 64 rows x 32 cols
    const int wrow = wid >> 2, wcol = wid & 3;
    const int col0 = lane & 15;
    const int quad = lane >> 4;
    const int rbase = bi * 128, cbase = bj * 128;
    const uint4* g = (const uint4*)fb;   // row stride = 16 uint4 (D=128 bf16)

    floatx4 acc[4][2];
    #pragma unroll
    for (int a = 0; a < 4; ++a)
        #pragma unroll
        for (int c = 0; c < 2; ++c)
            acc[a][c] = (floatx4){0.0f, 0.0f, 0.0f, 0.0f};

    #pragma unroll
    for (int ks = 0; ks < 4; ++ks) {     // K = 128 = 4 x 32
        int j = ks * 4 + quad;           // 16B chunk index within a 256B row
        bf16x8 af[4], bfr[2];
        #pragma unroll
        for (int mt = 0; mt < 4; ++mt) { // A[m=lane&15][k=quad*8+..]
            int r = rbase + wrow * 64 + mt * 16 + col0;
            af[mt] = *(const bf16x8*)&g[(size_t)r * 16 + j];
        }
        #pragma unroll
        for (int nt = 0; nt < 2; ++nt) { // B^T[n=lane&15][k]
            int c = cbase + wcol * 32 + nt * 16 + col0;
            bfr[nt] = *(const bf16x8*)&g[(size_t)c * 16 + j];
        }
        #pragma unroll
        for (int mt = 0; mt < 4; ++mt)
            #pragma unroll
            for (int nt = 0; nt < 2; ++nt)
                acc[mt][nt] = __builtin_amdgcn_mfma_f32_16x16x32_bf16(af[mt], bfr[nt], acc[mt][nt], 0, 0, 0);
    }

    // Epilogue: e = exp(sim); strict-upper mask only near the diagonal.
    // v[m], m = mt*4 + reg  <->  row = wrow*64 + (m>>2)*16 + quad*4 + (m&3)
    float v[16];
    float colpart[2];
    #pragma unroll
    for (int m = 0; m < 16; ++m) v[m] = 0.0f;
    colpart[0] = colpart[1] = 0.0f;

    if (bj > bi + 1) {                   // fast path: all strictly upper
        #pragma unroll
        for (int mt = 0; mt < 4; ++mt)
            #pragma unroll
            for (int nt = 0; nt < 2; ++nt)
                #pragma unroll
                for (int reg = 0; reg < 4; ++reg) {
                    float e = __expf(acc[mt][nt][reg]);
                    v[mt * 4 + reg] += e;
                    colpart[nt] += e;
                }
    } else {                             // diag / superdiag: mask + p extraction
        #pragma unroll
        for (int mt = 0; mt < 4; ++mt)
            #pragma unroll
            for (int nt = 0; nt < 2; ++nt)
                #pragma unroll
                for (int reg = 0; reg < 4; ++reg) {
                    int r = rbase + wrow * 64 + mt * 16 + quad * 4 + reg;  // C/D row
                    int c = cbase + wcol * 32 + nt * 16 + col0;            // C/D col
                    float s0 = acc[mt][nt][reg];
                    float e = __expf(s0);
                    if (c == r + 1) { p[r] = s0; ep[r] = e; }
                    e = (c > r) ? e : 0.0f;
                    v[mt * 4 + reg] += e;
                    colpart[nt] += e;
                }
    }

    // Row sums: value-halving butterfly over the 16 lanes of each quad group.
    // 15 shuffles instead of 64; lane ends holding the sum for m == col0.
    float v8[8];
    #pragma unroll
    for (int k = 0; k < 8; ++k) {
        float a = v[2 * k], bb = v[2 * k + 1];
        float give = (lane & 1) ? a : bb;
        float keep = (lane & 1) ? bb : a;
        v8[k] = keep + __shfl_xor(give, 1, 64);
    }
    float v4[4];
    #pragma unroll
    for (int k = 0; k < 4; ++k) {
        float a = v8[2 * k], bb = v8[2 * k + 1];
        float give = (lane & 2) ? a : bb;
        float keep = (lane & 2) ? bb : a;
        v4[k] = keep + __shfl_xor(give, 2, 64);
    }
    float v2[2];
    #pragma unroll
    for (int k = 0; k < 2; ++k) {
        float a = v4[2 * k], bb = v4[2 * k + 1];
        float give = (lane & 4) ? a : bb;
        float keep = (lane & 4) ? bb : a;
        v2[k] = keep + __shfl_xor(give, 4, 64);
    }
    {
        float a = v2[0], bb = v2[1];
        float give = (lane & 8) ? a : bb;
        float keep = (lane & 8) ? bb : a;
        float v1 = keep + __shfl_xor(give, 8, 64);
        int rowl = wrow * 64 + (col0 >> 2) * 16 + quad * 4 + (col0 & 3);
        PR[wcol][rowl] = v1;             // all 64 lanes write distinct rows
    }

    // Col sums: halving step over quad bit4, full reduce over bit5.
    {
        float give = (lane & 16) ? colpart[0] : colpart[1];
        float keep = (lane & 16) ? colpart[1] : colpart[0];
        float cv = keep + __shfl_xor(give, 16, 64);
        cv += __shfl_xor(cv, 32, 64);
        if (lane < 32)                   // cv holds col nt=(lane>>4), col0=lane&15
            PC[wrow][wcol * 32 + lane] = cv;
    }
    __syncthreads();

    // One coalesced partial store per block (no atomics).
    if (t < 128) {
        Prow[(size_t)b * 128 + t] = PR[0][t] + PR[1][t] + PR[2][t] + PR[3][t];
    } else if (t < 256) {
        int c = t - 128;
        Pcol[(size_t)b * 128 + c] = PC[0][c] + PC[1][c];
    }
}

// ---- Kernel 3: gather partials -> U[r] (strict-upper row sums), L[c] (col sums).
__global__ __launch_bounds__(256) void k_reduce(const float* __restrict__ Prow,
                                                const float* __restrict__ Pcol,
                                                float* __restrict__ U,
                                                float* __restrict__ L) {
    int tile = blockIdx.x;               // 0..63
    int tid = threadIdx.x;
    int base_t = tile * NTILES - tile * (tile - 1) / 2;
    if (tid < 128) {
        float s = 0.0f;
        for (int bj = tile; bj < NTILES; ++bj)
            s += Prow[(size_t)(base_t + bj - tile) * 128 + tid];
        U[tile * 128 + tid] = s;
    } else {
        int c = tid - 128;
        float s = 0.0f;
        for (int bi = 0; bi <= tile; ++bi) {
            int bb = bi * NTILES - bi * (bi - 1) / 2 + (tile - bi);
            s += Pcol[(size_t)bb * 128 + c];
        }
        L[tile * 128 + c] = s;
    }
}

// ---- Kernel 4: loss = sum_i log(U_i + L_{i+1} - ep_i) - p_i; out = -W*loss/N
__global__ __launch_bounds__(1024) void k_final(const float* __restrict__ U,
                                                const float* __restrict__ L,
                                                const float* __restrict__ p,
                                                const float* __restrict__ ep,
                                                float* __restrict__ out) {
    __shared__ float swred[16];
    float s = 0.0f;
    for (int i = threadIdx.x; i < N - 1; i += 1024) {
        float tt = U[i] + L[i + 1] - ep[i];
        s += __logf(tt) - p[i];
    }
    #pragma unroll
    for (int m = 1; m < 64; m <<= 1) s += __shfl_xor(s, m, 64);
    int lane = threadIdx.x & 63, wid = threadIdx.x >> 6;
    if (lane == 0) swred[wid] = s;
    __syncthreads();
    if (threadIdx.x == 0) {
        float tot = 0.0f;
        #pragma unroll
        for (int w = 0; w < 16; ++w) tot += swred[w];
        out[0] = -WEIGHT * tot / (float)N;
    }
}

extern "C" void kernel_launch(void* const* d_in, const int* in_sizes, int n_in,
                              void* d_out, int out_size, void* d_ws, size_t ws_size,
                              hipStream_t stream) {
    const float* x = (const float*)d_in[0];
    float* out = (float*)d_out;
    char* ws = (char*)d_ws;
    __hip_bfloat16* fb = (__hip_bfloat16*)ws;                  // N*D*2 = 2 MB
    float* p    = (float*)(ws + (size_t)N * D * 2);            // N floats
    float* ep   = p + N;
    float* U    = ep + N;
    float* L    = U + N;
    float* Prow = L + N;                                       // NBLK*128 floats
    float* Pcol = Prow + (size_t)NBLK * 128;

    hipLaunchKernelGGL(k_norm,   dim3(2048), dim3(256),  0, stream, x, fb);
    hipLaunchKernelGGL(k_gram,   dim3(NBLK), dim3(512),  0, stream, fb, Prow, Pcol, p, ep);
    hipLaunchKernelGGL(k_reduce, dim3(64),   dim3(256),  0, stream, Prow, Pcol, U, L);
    hipLaunchKernelGGL(k_final,  dim3(1),    dim3(1024), 0, stream, U, L, p, ep, out);
}

// Round 5
// 98.122 us; speedup vs baseline: 1.3338x; 1.3338x over previous
//
#include <hip/hip_runtime.h>
#include <hip/hip_bf16.h>

#define N 8192
#define D 128
#define WEIGHT 0.01f
#define NTILES 64            // N / 128
#define NBLK 2080            // NTILES*(NTILES+1)/2

typedef __bf16 bf16x8 __attribute__((ext_vector_type(8)));
typedef float floatx4 __attribute__((ext_vector_type(4)));

// ---- Kernel 1: L2-normalize rows (fp32) -> bf16, stored XOR-SWIZZLED:
//      16B chunk c of row r lands at chunk position c ^ (r & 15).
//      This lets k_gram copy rows to LDS linearly (global_load_lds) and still
//      get the conflict-free swizzled LDS layout verified in R2/R3.
__global__ __launch_bounds__(256) void k_norm(const float* __restrict__ x,
                                              __hip_bfloat16* __restrict__ fb) {
    int gid = blockIdx.x * 256 + threadIdx.x;   // 512 blocks -> 131072 threads
    int row = gid >> 4;                          // 16 threads per row
    int c   = gid & 15;                          // 16B chunk (8 bf16) per thread
    const float4* xr = (const float4*)(x + (size_t)row * D + c * 8);
    float4 f0 = xr[0], f1 = xr[1];
    float s = f0.x * f0.x + f0.y * f0.y + f0.z * f0.z + f0.w * f0.w
            + f1.x * f1.x + f1.y * f1.y + f1.z * f1.z + f1.w * f1.w;
    s += __shfl_xor(s, 1, 64);
    s += __shfl_xor(s, 2, 64);
    s += __shfl_xor(s, 4, 64);
    s += __shfl_xor(s, 8, 64);                   // 16-lane group = one row
    float inv = 1.0f / fmaxf(sqrtf(s), 1e-12f);
    union { __hip_bfloat16 h[8]; uint4 u; } pk;
    pk.h[0] = __float2bfloat16(f0.x * inv);
    pk.h[1] = __float2bfloat16(f0.y * inv);
    pk.h[2] = __float2bfloat16(f0.z * inv);
    pk.h[3] = __float2bfloat16(f0.w * inv);
    pk.h[4] = __float2bfloat16(f1.x * inv);
    pk.h[5] = __float2bfloat16(f1.y * inv);
    pk.h[6] = __float2bfloat16(f1.z * inv);
    pk.h[7] = __float2bfloat16(f1.w * inv);
    ((uint4*)fb)[(size_t)row * 16 + (c ^ (row & 15))] = pk.u;
}

// ---- Kernel 2: upper-triangle 128x128 tiles of sim = F F^T.
//      Staging: direct global->LDS (width=16) linear copy of the pre-swizzled
//      rows; no VGPR round-trip, no in-kernel swizzle math.
//      8 waves (2 wrow x 4 wcol), wave tile 64x32. LDS 67KB -> 2 blocks/CU.
__global__ __launch_bounds__(512, 4) void k_gram(const __hip_bfloat16* __restrict__ fb,
                                                 float* __restrict__ Prow,
                                                 float* __restrict__ Pcol,
                                                 float* __restrict__ p,
                                                 float* __restrict__ ep) {
    // Decode triangular linear index -> (bi, bj), bj >= bi.
    int b = blockIdx.x;                  // 0 .. 2079
    int bi = (int)((2.0 * NTILES + 1.0 - sqrt((2.0 * NTILES + 1.0) * (2.0 * NTILES + 1.0) - 8.0 * (double)b)) * 0.5);
    while (bi * NTILES - bi * (bi - 1) / 2 > b) --bi;
    while ((bi + 1) * NTILES - (bi + 1) * bi / 2 <= b) ++bi;
    int bj = bi + (b - (bi * NTILES - bi * (bi - 1) / 2));

    __shared__ uint4 Ab[128 * 16];       // pre-swizzled tile rows (32 KB)
    __shared__ uint4 Bb[128 * 16];
    __shared__ float PR[4][128];
    __shared__ float PC[2][128];

    const int t = threadIdx.x;
    const int lane = t & 63;
    const int wid  = t >> 6;             // 8 waves
    const int wrow = wid >> 2, wcol = wid & 3;
    const int col0 = lane & 15;
    const int quad = lane >> 4;
    const int rbase = bi * 128, cbase = bj * 128;

    const uint4* gA = (const uint4*)fb + (size_t)rbase * 16;   // 2048 chunks
    const uint4* gB = (const uint4*)fb + (size_t)cbase * 16;
    #pragma unroll
    for (int i = 0; i < 4; ++i) {
        int ca = wid * 256 + i * 64;     // wave-uniform chunk base; lane adds *16B
        __builtin_amdgcn_global_load_lds(
            (const __attribute__((address_space(1))) void*)(gA + ca + lane),
            (__attribute__((address_space(3))) void*)&Ab[ca], 16, 0, 0);
        __builtin_amdgcn_global_load_lds(
            (const __attribute__((address_space(1))) void*)(gB + ca + lane),
            (__attribute__((address_space(3))) void*)&Bb[ca], 16, 0, 0);
    }
    __syncthreads();

    floatx4 acc[4][2];
    #pragma unroll
    for (int a = 0; a < 4; ++a)
        #pragma unroll
        for (int c = 0; c < 2; ++c)
            acc[a][c] = (floatx4){0.0f, 0.0f, 0.0f, 0.0f};

    #pragma unroll
    for (int ks = 0; ks < 4; ++ks) {     // K = 128 = 4 x 32
        bf16x8 af[4], bfr[2];
        int j = ks * 4 + quad;
        int jsw = j ^ col0;              // fragment rows have (row & 15) == col0
        #pragma unroll
        for (int mt = 0; mt < 4; ++mt) { // A[m=lane&15][k=quad*8+..]
            int rl = wrow * 64 + mt * 16 + col0;
            af[mt] = *(const bf16x8*)&Ab[rl * 16 + jsw];
        }
        #pragma unroll
        for (int nt = 0; nt < 2; ++nt) { // B^T[n=lane&15][k]
            int cl = wcol * 32 + nt * 16 + col0;
            bfr[nt] = *(const bf16x8*)&Bb[cl * 16 + jsw];
        }
        #pragma unroll
        for (int mt = 0; mt < 4; ++mt)
            #pragma unroll
            for (int nt = 0; nt < 2; ++nt)
                acc[mt][nt] = __builtin_amdgcn_mfma_f32_16x16x32_bf16(af[mt], bfr[nt], acc[mt][nt], 0, 0, 0);
    }

    // Epilogue: e = exp(sim); strict-upper mask only near the diagonal.
    float v[16];                         // m = mt*4+reg -> row = wrow*64+(m>>2)*16+quad*4+(m&3)
    float colpart[2];
    #pragma unroll
    for (int m = 0; m < 16; ++m) v[m] = 0.0f;
    colpart[0] = colpart[1] = 0.0f;

    if (bj > bi + 1) {                   // fast path: all strictly upper
        #pragma unroll
        for (int mt = 0; mt < 4; ++mt)
            #pragma unroll
            for (int nt = 0; nt < 2; ++nt)
                #pragma unroll
                for (int reg = 0; reg < 4; ++reg) {
                    float e = __expf(acc[mt][nt][reg]);
                    v[mt * 4 + reg] += e;
                    colpart[nt] += e;
                }
    } else {                             // diag / superdiag: mask + p extraction
        #pragma unroll
        for (int mt = 0; mt < 4; ++mt)
            #pragma unroll
            for (int nt = 0; nt < 2; ++nt)
                #pragma unroll
                for (int reg = 0; reg < 4; ++reg) {
                    int r = rbase + wrow * 64 + mt * 16 + quad * 4 + reg;
                    int c = cbase + wcol * 32 + nt * 16 + col0;
                    float s0 = acc[mt][nt][reg];
                    float e = __expf(s0);
                    if (c == r + 1) { p[r] = s0; ep[r] = e; }
                    e = (c > r) ? e : 0.0f;
                    v[mt * 4 + reg] += e;
                    colpart[nt] += e;
                }
    }

    // Row sums: value-halving butterfly; 15 shuffles, all lanes end distinct rows.
    float v8[8];
    #pragma unroll
    for (int k = 0; k < 8; ++k) {
        float a = v[2 * k], bb = v[2 * k + 1];
        float give = (lane & 1) ? a : bb;
        float keep = (lane & 1) ? bb : a;
        v8[k] = keep + __shfl_xor(give, 1, 64);
    }
    float v4[4];
    #pragma unroll
    for (int k = 0; k < 4; ++k) {
        float a = v8[2 * k], bb = v8[2 * k + 1];
        float give = (lane & 2) ? a : bb;
        float keep = (lane & 2) ? bb : a;
        v4[k] = keep + __shfl_xor(give, 2, 64);
    }
    float v2[2];
    #pragma unroll
    for (int k = 0; k < 2; ++k) {
        float a = v4[2 * k], bb = v4[2 * k + 1];
        float give = (lane & 4) ? a : bb;
        float keep = (lane & 4) ? bb : a;
        v2[k] = keep + __shfl_xor(give, 4, 64);
    }
    {
        float a = v2[0], bb = v2[1];
        float give = (lane & 8) ? a : bb;
        float keep = (lane & 8) ? bb : a;
        float v1 = keep + __shfl_xor(give, 8, 64);
        int rowl = wrow * 64 + (col0 >> 2) * 16 + quad * 4 + (col0 & 3);
        PR[wcol][rowl] = v1;
    }
    // Col sums: halving over bit4, reduce over bit5.
    {
        float give = (lane & 16) ? colpart[0] : colpart[1];
        float keep = (lane & 16) ? colpart[1] : colpart[0];
        float cv = keep + __shfl_xor(give, 16, 64);
        cv += __shfl_xor(cv, 32, 64);
        if (lane < 32)
            PC[wrow][wcol * 32 + lane] = cv;
    }
    __syncthreads();

    if (t < 128) {
        Prow[(size_t)b * 128 + t] = PR[0][t] + PR[1][t] + PR[2][t] + PR[3][t];
    } else if (t < 256) {
        int c = t - 128;
        Pcol[(size_t)b * 128 + c] = PC[0][c] + PC[1][c];
    }
}

// ---- Kernel 3: gather partials -> U[r] (strict-upper row sums), L[c] (col sums).
__global__ __launch_bounds__(256) void k_reduce(const float* __restrict__ Prow,
                                                const float* __restrict__ Pcol,
                                                float* __restrict__ U,
                                                float* __restrict__ L) {
    int tile = blockIdx.x;               // 0..63
    int tid = threadIdx.x;
    int base_t = tile * NTILES - tile * (tile - 1) / 2;
    if (tid < 128) {
        float s = 0.0f;
        for (int bj = tile; bj < NTILES; ++bj)
            s += Prow[(size_t)(base_t + bj - tile) * 128 + tid];
        U[tile * 128 + tid] = s;
    } else {
        int c = tid - 128;
        float s = 0.0f;
        for (int bi = 0; bi <= tile; ++bi) {
            int bb = bi * NTILES - bi * (bi - 1) / 2 + (tile - bi);
            s += Pcol[(size_t)bb * 128 + c];
        }
        L[tile * 128 + c] = s;
    }
}

// ---- Kernel 4: loss = sum_i log(U_i + L_{i+1} - ep_i) - p_i; out = -W*loss/N
__global__ __launch_bounds__(1024) void k_final(const float* __restrict__ U,
                                                const float* __restrict__ L,
                                                const float* __restrict__ p,
                                                const float* __restrict__ ep,
                                                float* __restrict__ out) {
    __shared__ float swred[16];
    float s = 0.0f;
    for (int i = threadIdx.x; i < N - 1; i += 1024) {
        float tt = U[i] + L[i + 1] - ep[i];
        s += __logf(tt) - p[i];
    }
    #pragma unroll
    for (int m = 1; m < 64; m <<= 1) s += __shfl_xor(s, m, 64);
    int lane = threadIdx.x & 63, wid = threadIdx.x >> 6;
    if (lane == 0) swred[wid] = s;
    __syncthreads();
    if (threadIdx.x == 0) {
        float tot = 0.0f;
        #pragma unroll
        for (int w = 0; w < 16; ++w) tot += swred[w];
        out[0] = -WEIGHT * tot / (float)N;
    }
}

extern "C" void kernel_launch(void* const* d_in, const int* in_sizes, int n_in,
                              void* d_out, int out_size, void* d_ws, size_t ws_size,
                              hipStream_t stream) {
    const float* x = (const float*)d_in[0];
    float* out = (float*)d_out;
    char* ws = (char*)d_ws;
    __hip_bfloat16* fb = (__hip_bfloat16*)ws;                  // N*D*2 = 2 MB
    float* p    = (float*)(ws + (size_t)N * D * 2);            // N floats
    float* ep   = p + N;
    float* U    = ep + N;
    float* L    = U + N;
    float* Prow = L + N;                                       // NBLK*128 floats
    float* Pcol = Prow + (size_t)NBLK * 128;

    hipLaunchKernelGGL(k_norm,   dim3(512),  dim3(256),  0, stream, x, fb);
    hipLaunchKernelGGL(k_gram,   dim3(NBLK), dim3(512),  0, stream, fb, Prow, Pcol, p, ep);
    hipLaunchKernelGGL(k_reduce, dim3(64),   dim3(256),  0, stream, Prow, Pcol, U, L);
    hipLaunchKernelGGL(k_final,  dim3(1),    dim3(1024), 0, stream, U, L, p, ep, out);
}

// Round 6
// 96.932 us; speedup vs baseline: 1.3502x; 1.0123x over previous
//
#include <hip/hip_runtime.h>
#include <hip/hip_bf16.h>

#define N 8192
#define D 128
#define WEIGHT 0.01f
#define NTILES 64            // N / 128
#define NBLK 2080            // NTILES*(NTILES+1)/2

typedef __bf16 bf16x8 __attribute__((ext_vector_type(8)));
typedef float floatx4 __attribute__((ext_vector_type(4)));

// ---- Kernel 1: L2-normalize rows (fp32) -> bf16, stored XOR-SWIZZLED:
//      16B chunk c of row r lands at chunk position c ^ (r & 15), so k_gram's
//      linear global_load_lds copy produces the conflict-free LDS layout.
__global__ __launch_bounds__(256) void k_norm(const float* __restrict__ x,
                                              __hip_bfloat16* __restrict__ fb) {
    int gid = blockIdx.x * 256 + threadIdx.x;   // 512 blocks
    int row = gid >> 4;                          // 16 threads per row
    int c   = gid & 15;                          // 16B chunk (8 bf16) per thread
    const float4* xr = (const float4*)(x + (size_t)row * D + c * 8);
    float4 f0 = xr[0], f1 = xr[1];
    float s = f0.x * f0.x + f0.y * f0.y + f0.z * f0.z + f0.w * f0.w
            + f1.x * f1.x + f1.y * f1.y + f1.z * f1.z + f1.w * f1.w;
    s += __shfl_xor(s, 1, 64);
    s += __shfl_xor(s, 2, 64);
    s += __shfl_xor(s, 4, 64);
    s += __shfl_xor(s, 8, 64);                   // 16-lane group = one row
    float inv = 1.0f / fmaxf(sqrtf(s), 1e-12f);
    union { __hip_bfloat16 h[8]; uint4 u; } pk;
    pk.h[0] = __float2bfloat16(f0.x * inv);
    pk.h[1] = __float2bfloat16(f0.y * inv);
    pk.h[2] = __float2bfloat16(f0.z * inv);
    pk.h[3] = __float2bfloat16(f0.w * inv);
    pk.h[4] = __float2bfloat16(f1.x * inv);
    pk.h[5] = __float2bfloat16(f1.y * inv);
    pk.h[6] = __float2bfloat16(f1.z * inv);
    pk.h[7] = __float2bfloat16(f1.w * inv);
    ((uint4*)fb)[(size_t)row * 16 + (c ^ (row & 15))] = pk.u;
}

// ---- Kernel 2: upper-triangle 128x128 tiles of sim = F F^T.
//      4 waves (2x2), wave tile 64x64 (acc 4x4) -> 128 KB LDS reads per block
//      (vs 192 KB with 64x32 wave tiles). LDS 66 KB -> 2 blocks/CU; the
//      co-resident block hides staging drain.
__global__ __launch_bounds__(256, 2) void k_gram(const __hip_bfloat16* __restrict__ fb,
                                                 float* __restrict__ Prow,
                                                 float* __restrict__ Pcol,
                                                 float* __restrict__ p,
                                                 float* __restrict__ ep) {
    // Decode triangular linear index -> (bi, bj), bj >= bi.
    int b = blockIdx.x;                  // 0 .. 2079
    int bi = (int)((2.0 * NTILES + 1.0 - sqrt((2.0 * NTILES + 1.0) * (2.0 * NTILES + 1.0) - 8.0 * (double)b)) * 0.5);
    while (bi * NTILES - bi * (bi - 1) / 2 > b) --bi;
    while ((bi + 1) * NTILES - (bi + 1) * bi / 2 <= b) ++bi;
    int bj = bi + (b - (bi * NTILES - bi * (bi - 1) / 2));

    __shared__ uint4 Ab[128 * 16];       // pre-swizzled tile rows (32 KB)
    __shared__ uint4 Bb[128 * 16];
    __shared__ float PR[2][128];
    __shared__ float PC[2][128];

    const int t = threadIdx.x;
    const int lane = t & 63;
    const int wid  = t >> 6;             // 4 waves, 2x2
    const int wrow = wid >> 1, wcol = wid & 1;
    const int col0 = lane & 15;
    const int quad = lane >> 4;
    const int rbase = bi * 128, cbase = bj * 128;

    const uint4* gA = (const uint4*)fb + (size_t)rbase * 16;   // 2048 chunks
    const uint4* gB = (const uint4*)fb + (size_t)cbase * 16;
    #pragma unroll
    for (int i = 0; i < 8; ++i) {
        int ca = wid * 512 + i * 64;     // wave-uniform chunk base; lane adds *16B
        __builtin_amdgcn_global_load_lds(
            (const __attribute__((address_space(1))) void*)(gA + ca + lane),
            (__attribute__((address_space(3))) void*)&Ab[ca], 16, 0, 0);
        __builtin_amdgcn_global_load_lds(
            (const __attribute__((address_space(1))) void*)(gB + ca + lane),
            (__attribute__((address_space(3))) void*)&Bb[ca], 16, 0, 0);
    }
    __syncthreads();

    floatx4 acc[4][4];
    #pragma unroll
    for (int a = 0; a < 4; ++a)
        #pragma unroll
        for (int c = 0; c < 4; ++c)
            acc[a][c] = (floatx4){0.0f, 0.0f, 0.0f, 0.0f};

    #pragma unroll
    for (int ks = 0; ks < 4; ++ks) {     // K = 128 = 4 x 32
        bf16x8 af[4], bfr[4];
        int j = ks * 4 + quad;
        int jsw = j ^ col0;              // fragment rows have (row & 15) == col0
        #pragma unroll
        for (int mt = 0; mt < 4; ++mt) { // A[m=lane&15][k=quad*8+..]
            int rl = wrow * 64 + mt * 16 + col0;
            af[mt] = *(const bf16x8*)&Ab[rl * 16 + jsw];
        }
        #pragma unroll
        for (int nt = 0; nt < 4; ++nt) { // B^T[n=lane&15][k]
            int cl = wcol * 64 + nt * 16 + col0;
            bfr[nt] = *(const bf16x8*)&Bb[cl * 16 + jsw];
        }
        #pragma unroll
        for (int mt = 0; mt < 4; ++mt)
            #pragma unroll
            for (int nt = 0; nt < 4; ++nt)
                acc[mt][nt] = __builtin_amdgcn_mfma_f32_16x16x32_bf16(af[mt], bfr[nt], acc[mt][nt], 0, 0, 0);
    }

    // Epilogue: e = exp(sim); strict-upper mask only near the diagonal.
    float v[16];                         // m = mt*4+reg -> row = wrow*64+(m>>2)*16+quad*4+(m&3)
    float colpart[4];                    // nt -> col = wcol*64 + nt*16 + col0
    #pragma unroll
    for (int m = 0; m < 16; ++m) v[m] = 0.0f;
    #pragma unroll
    for (int m = 0; m < 4; ++m) colpart[m] = 0.0f;

    if (bj > bi + 1) {                   // fast path: all strictly upper
        #pragma unroll
        for (int mt = 0; mt < 4; ++mt)
            #pragma unroll
            for (int nt = 0; nt < 4; ++nt)
                #pragma unroll
                for (int reg = 0; reg < 4; ++reg) {
                    float e = __expf(acc[mt][nt][reg]);
                    v[mt * 4 + reg] += e;
                    colpart[nt] += e;
                }
    } else {                             // diag / superdiag: mask + p extraction
        #pragma unroll
        for (int mt = 0; mt < 4; ++mt)
            #pragma unroll
            for (int nt = 0; nt < 4; ++nt)
                #pragma unroll
                for (int reg = 0; reg < 4; ++reg) {
                    int r = rbase + wrow * 64 + mt * 16 + quad * 4 + reg;
                    int c = cbase + wcol * 64 + nt * 16 + col0;
                    float s0 = acc[mt][nt][reg];
                    float e = __expf(s0);
                    if (c == r + 1) { p[r] = s0; ep[r] = e; }
                    e = (c > r) ? e : 0.0f;
                    v[mt * 4 + reg] += e;
                    colpart[nt] += e;
                }
    }

    // Row sums: value-halving butterfly; 15 shuffles, all lanes end distinct rows.
    float v8[8];
    #pragma unroll
    for (int k = 0; k < 8; ++k) {
        float a = v[2 * k], bb = v[2 * k + 1];
        float give = (lane & 1) ? a : bb;
        float keep = (lane & 1) ? bb : a;
        v8[k] = keep + __shfl_xor(give, 1, 64);
    }
    float v4[4];
    #pragma unroll
    for (int k = 0; k < 4; ++k) {
        float a = v8[2 * k], bb = v8[2 * k + 1];
        float give = (lane & 2) ? a : bb;
        float keep = (lane & 2) ? bb : a;
        v4[k] = keep + __shfl_xor(give, 2, 64);
    }
    float v2[2];
    #pragma unroll
    for (int k = 0; k < 2; ++k) {
        float a = v4[2 * k], bb = v4[2 * k + 1];
        float give = (lane & 4) ? a : bb;
        float keep = (lane & 4) ? bb : a;
        v2[k] = keep + __shfl_xor(give, 4, 64);
    }
    {
        float a = v2[0], bb = v2[1];
        float give = (lane & 8) ? a : bb;
        float keep = (lane & 8) ? bb : a;
        float v1 = keep + __shfl_xor(give, 8, 64);
        int rowl = wrow * 64 + (col0 >> 2) * 16 + quad * 4 + (col0 & 3);
        PR[wcol][rowl] = v1;
    }
    // Col sums: value-halving over lane bit4 then bit5; lane ends holding
    // nt == quad, i.e. col = wcol*64 + lane.
    {
        float c2[2];
        #pragma unroll
        for (int k = 0; k < 2; ++k) {
            float a = colpart[2 * k];        // nt even
            float bb = colpart[2 * k + 1];   // nt odd
            float give = (lane & 16) ? a : bb;
            float keep = (lane & 16) ? bb : a;
            c2[k] = keep + __shfl_xor(give, 16, 64);
        }
        float a = c2[0], bb = c2[1];
        float give = (lane & 32) ? a : bb;
        float keep = (lane & 32) ? bb : a;
        float cv = keep + __shfl_xor(give, 32, 64);
        PC[wrow][wcol * 64 + lane] = cv;
    }
    __syncthreads();

    if (t < 128) {
        Prow[(size_t)b * 128 + t] = PR[0][t] + PR[1][t];
    } else {
        int c = t - 128;
        Pcol[(size_t)b * 128 + c] = PC[0][c] + PC[1][c];
    }
}

// ---- Kernel 3: gather partials -> U[r] (strict-upper row sums), L[c] (col sums).
__global__ __launch_bounds__(256) void k_reduce(const float* __restrict__ Prow,
                                                const float* __restrict__ Pcol,
                                                float* __restrict__ U,
                                                float* __restrict__ L) {
    int tile = blockIdx.x;               // 0..63
    int tid = threadIdx.x;
    int base_t = tile * NTILES - tile * (tile - 1) / 2;
    if (tid < 128) {
        float s = 0.0f;
        for (int bj = tile; bj < NTILES; ++bj)
            s += Prow[(size_t)(base_t + bj - tile) * 128 + tid];
        U[tile * 128 + tid] = s;
    } else {
        int c = tid - 128;
        float s = 0.0f;
        for (int bi = 0; bi <= tile; ++bi) {
            int bb = bi * NTILES - bi * (bi - 1) / 2 + (tile - bi);
            s += Pcol[(size_t)bb * 128 + c];
        }
        L[tile * 128 + c] = s;
    }
}

// ---- Kernel 4: loss = sum_i log(U_i + L_{i+1} - ep_i) - p_i; out = -W*loss/N
__global__ __launch_bounds__(1024) void k_final(const float* __restrict__ U,
                                                const float* __restrict__ L,
                                                const float* __restrict__ p,
                                                const float* __restrict__ ep,
                                                float* __restrict__ out) {
    __shared__ float swred[16];
    float s = 0.0f;
    for (int i = threadIdx.x; i < N - 1; i += 1024) {
        float tt = U[i] + L[i + 1] - ep[i];
        s += __logf(tt) - p[i];
    }
    #pragma unroll
    for (int m = 1; m < 64; m <<= 1) s += __shfl_xor(s, m, 64);
    int lane = threadIdx.x & 63, wid = threadIdx.x >> 6;
    if (lane == 0) swred[wid] = s;
    __syncthreads();
    if (threadIdx.x == 0) {
        float tot = 0.0f;
        #pragma unroll
        for (int w = 0; w < 16; ++w) tot += swred[w];
        out[0] = -WEIGHT * tot / (float)N;
    }
}

extern "C" void kernel_launch(void* const* d_in, const int* in_sizes, int n_in,
                              void* d_out, int out_size, void* d_ws, size_t ws_size,
                              hipStream_t stream) {
    const float* x = (const float*)d_in[0];
    float* out = (float*)d_out;
    char* ws = (char*)d_ws;
    __hip_bfloat16* fb = (__hip_bfloat16*)ws;                  // N*D*2 = 2 MB
    float* p    = (float*)(ws + (size_t)N * D * 2);            // N floats
    float* ep   = p + N;
    float* U    = ep + N;
    float* L    = U + N;
    float* Prow = L + N;                                       // NBLK*128 floats
    float* Pcol = Prow + (size_t)NBLK * 128;

    hipLaunchKernelGGL(k_norm,   dim3(512),  dim3(256),  0, stream, x, fb);
    hipLaunchKernelGGL(k_gram,   dim3(NBLK), dim3(256),  0, stream, fb, Prow, Pcol, p, ep);
    hipLaunchKernelGGL(k_reduce, dim3(64),   dim3(256),  0, stream, Prow, Pcol, U, L);
    hipLaunchKernelGGL(k_final,  dim3(1),    dim3(1024), 0, stream, U, L, p, ep, out);
}